// Round 7
// baseline (7317.463 us; speedup 1.0000x reference)
//
#include <hip/hip_runtime.h>
#include <cstdint>
#include <cstddef>

// ---------------------------------------------------------------------------
// RNNModel: 2-layer bidirectional GRU (B=64, T=1000, H=256) + FC(512->61) +
// length-gather.
// Round 7 (R6 was gi-HBM-stream-bound: FETCH 385MB = full fp32 gi, 8 CUs at
// per-CU HBM ceiling):
//  - gi ALWAYS bf16 (197 MB, halves stream bytes)
//  - 32 GRU WGs (2 dir x 16 sample-groups of 4): 4x CUs pulling HBM,
//    per-WG stream 6 KB/step
//  - gi layout [sg*2+dir][t][768][4]: per-WG stream fully contiguous ->
//    full cache lines, no cross-XCD line sharing
//  - GEMM grid swapped to (n-tiles, t-tiles): t-major write order -> high-t
//    L3-resident at GRU launch (bwd streams hit, like R4's accidental win)
//  - one-step-ahead gi register prefetch
//  - W_hh: 48 B-frags/wave pinned in regs (R6 mechanism, kept)
// ---------------------------------------------------------------------------

typedef __attribute__((ext_vector_type(8))) __bf16 bf16x8;
typedef __attribute__((ext_vector_type(4))) float f32x4;
typedef __attribute__((ext_vector_type(4))) unsigned int u32x4;
typedef __attribute__((ext_vector_type(2))) unsigned int u32x2;

#define AS1 __attribute__((address_space(1)))
#define AS3 __attribute__((address_space(3)))

#define SRZ  (-1.44269504089f)   // exp2 prescale for r,z rows
#define SN   (2.88539008177f)    // exp2 prescale for n rows

__device__ __forceinline__ void async_ld16(const void* g, void* l) {
  __builtin_amdgcn_global_load_lds((const AS1 unsigned int*)g,
                                   (AS3 unsigned int*)l, 16, 0, 0);
}

__device__ __forceinline__ f32x4 mfma16(u32x4 a, u32x4 b, f32x4 c) {
  return __builtin_amdgcn_mfma_f32_16x16x32_bf16(
      __builtin_bit_cast(bf16x8, a), __builtin_bit_cast(bf16x8, b), c, 0, 0, 0);
}

__device__ __forceinline__ unsigned short f2b(float f) {  // f32 -> bf16 RNE
  unsigned int u = __float_as_uint(f);
  u += 0x7fffu + ((u >> 16) & 1u);
  return (unsigned short)(u >> 16);
}
// element r (0..3) of a 4xbf16 pack
__device__ __forceinline__ float bfel(u32x2 v, int r) {
  const unsigned int x = v[r >> 1];
  return __uint_as_float((r & 1) ? (x & 0xffff0000u) : (x << 16));
}

__device__ __forceinline__ float sigm2(float xs) {  // sigma(x), xs = -log2e*x
  return __builtin_amdgcn_rcpf(1.0f + __builtin_amdgcn_exp2f(xs));
}
__device__ __forceinline__ float tanh2(float ys) {  // tanh(y), ys = 2log2e*y
  return __builtin_fmaf(-2.0f,
      __builtin_amdgcn_rcpf(1.0f + __builtin_amdgcn_exp2f(ys)), 1.0f);
}

// lgkm-only barrier: don't drain vmcnt (stores/prefetch stay in flight)
__device__ __forceinline__ void lds_barrier() {
  asm volatile("" ::: "memory");
  __builtin_amdgcn_s_waitcnt(0xC07F);  // vmcnt=63, expcnt=7, lgkmcnt=0
  __builtin_amdgcn_s_barrier();
  asm volatile("" ::: "memory");
}

// ---------------------------------------------------------------------------
__global__ void cast_bf16_kernel(const float* __restrict__ src,
                                 unsigned short* __restrict__ dst, int n) {
  const int i = blockIdx.x * 256 + threadIdx.x;
  if (i < n) dst[i] = f2b(src[i]);
}

// weight cast with per-gate-row exp2 prescale. rows: [0,512) r,z ; [512,768) n
__global__ void cast_w_kernel(const float* __restrict__ src,
                              unsigned short* __restrict__ dst, int n,
                              int in_dim) {
  const int i = blockIdx.x * 256 + threadIdx.x;
  if (i < n) {
    const int row = (i / in_dim) % 768;
    const float s = (row < 512) ? SRZ : SN;
    dst[i] = f2b(s * src[i]);
  }
}

// fused GEMM bias: scaled (b_ih + b_hh) for r,z rows; scaled b_ih for n rows
__global__ void bias_fuse_kernel(const float* __restrict__ bih,
                                 const float* __restrict__ bhh,
                                 float* __restrict__ fb) {
  const int n = blockIdx.x * 256 + threadIdx.x;  // 0..1535
  if (n < 1536) {
    const int dir = n / 768;
    const int rr = n - dir * 768;
    const float s = (rr < 512) ? SRZ : SN;
    float v = bih[dir * 768 + rr];
    if (rr < 512) v += bhh[dir * 768 + rr];
    fb[n] = s * v;
  }
}

// batch [B,T,8,40] -> x [T,B,320] bf16, x[t,b,f*8+c] = batch[b,t,c,f]
__global__ void transpose_x_kernel(const float* __restrict__ batch,
                                   unsigned short* __restrict__ xb) {
  const int t = blockIdx.x, b = blockIdx.y, i = threadIdx.x;  // block 320
  const float v = batch[((size_t)b * 1000 + t) * 320 + (i & 7) * 40 + (i >> 3)];
  xb[((size_t)t * 64 + b) * 320 + i] = f2b(v);
}

// ---------------------------------------------------------------------------
// gi[(sg*2+dir)][t][768][4] bf16 = A[t*64+b][:] . W[n][:] + bias[n]
// (b = sg*4+r, n = dir*768+gr). A[M,K],W[N,K] bf16. 128x128 tile, BK=32,
// 256 thr, m97 recipe. Grid (12 n-tiles, 500 t-tiles): t-major write order.
__global__ __launch_bounds__(256) void gemm_bt_kernel(
    const unsigned short* __restrict__ A, const unsigned short* __restrict__ W,
    const float* __restrict__ bias, unsigned short* __restrict__ C,
    int M, int N, int K) {
  __shared__ __align__(16) unsigned short As[4096];
  __shared__ __align__(16) unsigned short Bs[4096];
  const int tid = threadIdx.x;
  const int lane = tid & 63;
  const int wv = tid >> 6;
  const int mBase = blockIdx.y * 128;  // m/t-tiles on y (slow) -> t-major
  const int nBase = blockIdx.x * 128;  // n-tiles on x (fast)

  const int s0 = tid, s1 = tid + 256;
  const int r0 = ((s0 >> 6) << 4) | (s0 & 15), c0 = ((s0 >> 4) & 3) * 8;
  const int r1 = ((s1 >> 6) << 4) | (s1 & 15), c1 = ((s1 >> 4) & 3) * 8;

  const unsigned short* Arow0 = A + (size_t)(mBase + r0) * K + c0;
  const unsigned short* Arow1 = A + (size_t)(mBase + r1) * K + c1;
  const unsigned short* Wrow0 = W + (size_t)(nBase + r0) * K + c0;
  const unsigned short* Wrow1 = W + (size_t)(nBase + r1) * K + c1;

  char* lA = (char*)As;
  char* lB = (char*)Bs;
  char* dstA0 = lA + wv * 1024;
  char* dstA1 = lA + 4096 + wv * 1024;
  char* dstB0 = lB + wv * 1024;
  char* dstB1 = lB + 4096 + wv * 1024;

  f32x4 acc[4][4] = {};
  const int mh = (wv >> 1) * 64, nh = (wv & 1) * 64;
  const u32x4* As4 = (const u32x4*)As;
  const u32x4* Bs4 = (const u32x4*)Bs;

  for (int k0 = 0; k0 < K; k0 += 32) {
    __syncthreads();
    async_ld16(Arow0 + k0, dstA0);
    async_ld16(Arow1 + k0, dstA1);
    async_ld16(Wrow0 + k0, dstB0);
    async_ld16(Wrow1 + k0, dstB1);
    __syncthreads();
    u32x4 a[4], b[4];
#pragma unroll
    for (int mt = 0; mt < 4; ++mt) a[mt] = As4[((mh >> 4) + mt) * 64 + lane];
#pragma unroll
    for (int nt = 0; nt < 4; ++nt) b[nt] = Bs4[((nh >> 4) + nt) * 64 + lane];
#pragma unroll
    for (int mt = 0; mt < 4; ++mt)
#pragma unroll
      for (int nt = 0; nt < 4; ++nt)
        acc[mt][nt] = mfma16(a[mt], b[nt], acc[mt][nt]);
  }
  // epilogue: 4 consecutive b = one sg's 4 samples -> one 8B bf16 store;
  // lanes c=0..15 (consecutive gr) write contiguous 128 B.
#pragma unroll
  for (int nt = 0; nt < 4; ++nt) {
    const int n = nBase + nh + nt * 16 + (lane & 15);
    const float bn = bias[n];
    const int dirx = (n >= 768) ? 1 : 0;
    const int gr = n - dirx * 768;
#pragma unroll
    for (int mt = 0; mt < 4; ++mt) {
      const int mrow = mBase + mh + mt * 16 + ((lane >> 4) << 2);
      const int t = mrow >> 6, bb = mrow & 63;
      const int sgx = bb >> 2;
      const f32x4 v = acc[mt][nt];
      u32x2 o;
      o[0] = (unsigned int)f2b(v[0] + bn) | ((unsigned int)f2b(v[1] + bn) << 16);
      o[1] = (unsigned int)f2b(v[2] + bn) | ((unsigned int)f2b(v[3] + bn) << 16);
      *(u32x2*)(C + (((size_t)(sgx * 2 + dirx) * 1000 + t) * 768 + gr) * 4) = o;
    }
  }
}

// ---------------------------------------------------------------------------
// GRU layer, 32 WGs: sg = bx>>1 (4 samples sb=sg*4), dir = bx&1. 512 thr =
// 8 waves; wave w owns units [32w,32w+32): 48 B-frags pinned in regs (R6
// mechanism). A-tile rows 0..3 = live samples, rows 4..15 stay zero.
// h-LDS double buffer [2][16][288] u16; ONE lgkm barrier/step. Only q==0
// lanes (C-rows 0..3) do gi loads + gate math + h writes.
__global__ __launch_bounds__(512, 2) void gru_s4_kernel(
    const unsigned short* __restrict__ gi,   // [32][1000][768][4] bf16
    const unsigned short* __restrict__ whh,  // [2][768][256] bf16 prescaled
    const float* __restrict__ bhh,           // [2][768] raw
    unsigned short* __restrict__ hout) {     // [T*B][512] bf16
  __shared__ __align__(16) char smem[18432];  // 2 x 16 x 576
  const int tid = threadIdx.x;
  const int lane = tid & 63;
  const int w = tid >> 6;   // 0..7
  const int c = lane & 15;
  const int q = lane >> 4;  // 0..3
  const int bx = blockIdx.x;
  const int dir = bx & 1;
  const int sg = bx >> 1;   // 0..15
  const int sb = sg * 4;

  for (int i = tid; i < 4608; i += 512) ((unsigned int*)smem)[i] = 0u;

  const int u0 = 32 * w + c;  // j=0 unit; j=1 is u0+16
  const float bhn0 = SN * bhh[dir * 768 + 512 + u0];
  const float bhn1 = SN * bhh[dir * 768 + 512 + u0 + 16];

  // B-frags (j,g,kt): row = g*256 + u0 + 16j, k = kt*32 + q*8
  const unsigned short* wb =
      whh + (size_t)dir * 196608 + (size_t)u0 * 256 + q * 8;
  u32x4 wvf[2][3][8];
#pragma unroll
  for (int j = 0; j < 2; ++j)
#pragma unroll
    for (int g = 0; g < 3; ++g) {
      const unsigned short* p = wb + (size_t)(g * 256 + 16 * j) * 256;
#pragma unroll
      for (int kt = 0; kt < 8; ++kt) wvf[j][g][kt] = *(const u32x4*)(p + kt * 32);
    }
#pragma unroll
  for (int j = 0; j < 2; ++j)
#pragma unroll
    for (int g = 0; g < 3; ++g)
#pragma unroll
      for (int kt = 0; kt < 8; ++kt)
        asm volatile("" : "+v"(wvf[j][g][kt]));  // pin: no in-loop remat

  float h0[4] = {0.f, 0.f, 0.f, 0.f}, h1v[4] = {0.f, 0.f, 0.f, 0.f};
  __syncthreads();

  const int t0 = dir ? 999 : 0;
  // stream element: ((sg*2+dir)*1000 + t)*3072 + (g*256+u)*4 + r
  const unsigned short* gp =
      gi + ((size_t)(sg * 2 + dir) * 1000 + t0) * 3072 + u0 * 4;
  unsigned short* hp = hout + ((size_t)t0 * 64 + sb) * 512 + dir * 256 + u0;
  const ptrdiff_t gstep = (dir ? -1 : 1) * (ptrdiff_t)3072;
  const ptrdiff_t hstep = (dir ? -1 : 1) * (ptrdiff_t)(64 * 512);

  // prefetch step-0 gi (q==0 lanes; lanes c=0..15 -> contiguous 128B/load)
  u32x2 p[2][3];
  if (q == 0) {
#pragma unroll
    for (int j = 0; j < 2; ++j)
#pragma unroll
      for (int g = 0; g < 3; ++g)
        p[j][g] = *(const u32x2*)(gp + g * 1024 + j * 64);
  }

  const int hw0 = u0;  // h-LDS write col

  for (int st = 0; st < 1000; ++st) {
    const int par = st & 1;
    const char* abuf = smem + (par ^ 1) * 9216;  // h(st-1)
    char* wbuf = (char*)smem + par * 9216;       // h(st)

    lds_barrier();  // prev writes visible; prev reads retired

    // A-frags: sample=c, k = q*8 + kt*32
    const char* hab = abuf + c * 576 + q * 16;
    u32x4 a[8];
#pragma unroll
    for (int kt = 0; kt < 8; ++kt) a[kt] = *(const u32x4*)(hab + kt * 64);

    // prefetch next step's gi (in-bounds even at st=999: lands in the
    // adjacent stream's region inside gi)
    u32x2 pn[2][3];
    if (q == 0) {
      const unsigned short* gn = gp + gstep;
#pragma unroll
      for (int j = 0; j < 2; ++j)
#pragma unroll
        for (int g = 0; g < 3; ++g)
          pn[j][g] = *(const u32x2*)(gn + g * 1024 + j * 64);
    }

    f32x4 acc[2][3] = {};
#pragma unroll
    for (int kt = 0; kt < 8; ++kt)
#pragma unroll
      for (int j = 0; j < 2; ++j)
#pragma unroll
        for (int g = 0; g < 3; ++g)
          acc[j][g] = mfma16(a[kt], wvf[j][g][kt], acc[j][g]);

    if (q == 0) {
      unsigned short* hls = (unsigned short*)wbuf;
#pragma unroll
      for (int r = 0; r < 4; ++r) {  // sample s = r (C-row = reg, q=0)
        const float rr0 = sigm2(bfel(p[0][0], r) + acc[0][0][r]);
        const float zz0 = sigm2(bfel(p[0][1], r) + acc[0][1][r]);
        const float nn0 =
            tanh2(__builtin_fmaf(rr0, acc[0][2][r] + bhn0, bfel(p[0][2], r)));
        const float hv0 = __builtin_fmaf(zz0, h0[r] - nn0, nn0);
        h0[r] = hv0;
        const float rr1 = sigm2(bfel(p[1][0], r) + acc[1][0][r]);
        const float zz1 = sigm2(bfel(p[1][1], r) + acc[1][1][r]);
        const float nn1 =
            tanh2(__builtin_fmaf(rr1, acc[1][2][r] + bhn1, bfel(p[1][2], r)));
        const float hv1 = __builtin_fmaf(zz1, h1v[r] - nn1, nn1);
        h1v[r] = hv1;
        const unsigned short hb0 = f2b(hv0), hb1 = f2b(hv1);
        hls[r * 288 + hw0] = hb0;
        hls[r * 288 + hw0 + 16] = hb1;
        hp[(size_t)r * 512] = hb0;
        hp[(size_t)r * 512 + 16] = hb1;
      }
#pragma unroll
      for (int j = 0; j < 2; ++j)
#pragma unroll
        for (int g = 0; g < 3; ++g) p[j][g] = pn[j][g];
    }
    gp += gstep;
    hp += hstep;
  }
}

// ---------------------------------------------------------------------------
__global__ void prefix_kernel(const int* __restrict__ raw,
                              int* __restrict__ pref, int* __restrict__ lens) {
  if (threadIdx.x == 0) {
    const int stride = (raw[1] == 0 && raw[3] == 0 && raw[5] == 0) ? 2 : 1;
    int a = 0;
    for (int b = 0; b < 64; ++b) {
      const int L = raw[b * stride];
      pref[b] = a;
      lens[b] = L;
      a += L;
    }
  }
}

__global__ __launch_bounds__(256) void fc_kernel(
    const unsigned short* __restrict__ h2, const unsigned short* __restrict__ fcw,
    const float* __restrict__ fcb, const int* __restrict__ lens,
    const int* __restrict__ pref, float* __restrict__ out) {
  __shared__ __align__(16) unsigned short hrow[4][512];
  const int b = blockIdx.y;
  const int sub = threadIdx.x >> 6, lane = threadIdx.x & 63;
  const int t = blockIdx.x * 4 + sub;
  *(u32x4*)&hrow[sub][lane * 8] =
      *(const u32x4*)&h2[((size_t)t * 64 + b) * 512 + lane * 8];
  __syncthreads();
  const int len = lens[b];
  if (lane < 61 && t < len) {
    float acc = fcb[lane];
    const unsigned short* wr = fcw + (size_t)lane * 512;
#pragma unroll 4
    for (int k = 0; k < 512; k += 8) {
      u32x4 w4 = *(const u32x4*)(wr + k);
      u32x4 h4 = *(const u32x4*)(&hrow[sub][k]);
#pragma unroll
      for (int qq = 0; qq < 4; ++qq) {
        acc += __uint_as_float(w4[qq] << 16) * __uint_as_float(h4[qq] << 16);
        acc += __uint_as_float(w4[qq] & 0xffff0000u) * __uint_as_float(h4[qq] & 0xffff0000u);
      }
    }
    out[((size_t)pref[b] + t) * 61 + lane] = acc;
  }
}

// ---------------------------------------------------------------------------
extern "C" void kernel_launch(void* const* d_in, const int* in_sizes, int n_in,
                              void* d_out, int out_size, void* d_ws, size_t ws_size,
                              hipStream_t stream) {
  (void)in_sizes; (void)n_in; (void)out_size; (void)ws_size;
  const float* batch   = (const float*)d_in[0];
  const int*   lengths = (const int*)d_in[1];
  const float* w_ih_l0 = (const float*)d_in[2];
  const float* w_hh_l0 = (const float*)d_in[3];
  const float* b_ih_l0 = (const float*)d_in[4];
  const float* b_hh_l0 = (const float*)d_in[5];
  const float* w_ih_l1 = (const float*)d_in[6];
  const float* w_hh_l1 = (const float*)d_in[7];
  const float* b_ih_l1 = (const float*)d_in[8];
  const float* b_hh_l1 = (const float*)d_in[9];
  const float* fc_w    = (const float*)d_in[10];
  const float* fc_b    = (const float*)d_in[11];
  float* out = (float*)d_out;
  char* ws = (char*)d_ws;

  size_t off = 0;
  auto alloc = [&](size_t bytes) -> char* {
    char* p = ws + off;
    off += (bytes + 255) & ~(size_t)255;
    return p;
  };
  char* pool = alloc((size_t)64000 * 512 * 2);  // xb/h1/h2 liveness-disjoint
  unsigned short* xb = (unsigned short*)pool;
  unsigned short* h1 = (unsigned short*)pool;
  unsigned short* h2 = (unsigned short*)pool;
  unsigned short* gi   = (unsigned short*)alloc((size_t)64000 * 1536 * 2);  // 197MB
  unsigned short* wih0 = (unsigned short*)alloc((size_t)1536 * 320 * 2);
  unsigned short* wih1 = (unsigned short*)alloc((size_t)1536 * 512 * 2);
  unsigned short* whh0 = (unsigned short*)alloc((size_t)1536 * 256 * 2);
  unsigned short* whh1 = (unsigned short*)alloc((size_t)1536 * 256 * 2);
  unsigned short* fcwb = (unsigned short*)alloc((size_t)61 * 512 * 2);
  float*          fb0  = (float*)alloc(1536 * 4);
  float*          fb1  = (float*)alloc(1536 * 4);
  int*            pref = (int*)alloc(256);
  int*            lens = (int*)alloc(256);

  auto castw = [&](const float* s, unsigned short* d, int n, int in_dim) {
    cast_w_kernel<<<dim3((n + 255) / 256), dim3(256), 0, stream>>>(s, d, n, in_dim);
  };
  castw(w_ih_l0, wih0, 2 * 768 * 320, 320);
  castw(w_hh_l0, whh0, 2 * 768 * 256, 256);
  castw(w_ih_l1, wih1, 2 * 768 * 512, 512);
  castw(w_hh_l1, whh1, 2 * 768 * 256, 256);
  cast_bf16_kernel<<<dim3((61 * 512 + 255) / 256), dim3(256), 0, stream>>>(
      fc_w, fcwb, 61 * 512);
  bias_fuse_kernel<<<dim3(6), dim3(256), 0, stream>>>(b_ih_l0, b_hh_l0, fb0);
  bias_fuse_kernel<<<dim3(6), dim3(256), 0, stream>>>(b_ih_l1, b_hh_l1, fb1);

  transpose_x_kernel<<<dim3(1000, 64), dim3(320), 0, stream>>>(batch, xb);

  // grid (n-tiles=12 on x, t-tiles=500 on y): x-fastest dispatch => t-major
  gemm_bt_kernel<<<dim3(12, 500), dim3(256), 0, stream>>>(
      xb, wih0, fb0, gi, 64000, 1536, 320);
  gru_s4_kernel<<<dim3(32), dim3(512), 0, stream>>>(gi, whh0, b_hh_l0, h1);
  gemm_bt_kernel<<<dim3(12, 500), dim3(256), 0, stream>>>(
      h1, wih1, fb1, gi, 64000, 1536, 512);
  gru_s4_kernel<<<dim3(32), dim3(512), 0, stream>>>(gi, whh1, b_hh_l1, h2);

  prefix_kernel<<<dim3(1), dim3(64), 0, stream>>>(lengths, pref, lens);
  fc_kernel<<<dim3(250, 64), dim3(256), 0, stream>>>(h2, fcwb, fc_b, lens, pref, out);
}